// Round 4
// baseline (152.068 us; speedup 1.0000x reference)
//
#include <hip/hip_runtime.h>

// out[b, i, j] = x[b, i + j];  B=128, L=8192, W=31, n_win = 8162.
// Write-BW-bound broadcast. One float4 (4 outputs) per thread, flat layout.
// Indexing: one magic-div pair per thread (not per element); remaining source
// addresses derived incrementally. Batch-row crossing is rare (127 threads) —
// predicated slow path. Nontemporal stores: output is never re-read.

typedef float vfloat4 __attribute__((ext_vector_type(4)));   // native vector for nt-store

constexpr unsigned B_   = 128;
constexpr unsigned L_   = 8192;
constexpr unsigned W_   = 31;
constexpr unsigned NWIN = L_ - (W_ - 1);       // 8162
constexpr unsigned PERB = NWIN * W_;           // 253022 floats per batch row
constexpr unsigned TOTAL = B_ * PERB;          // 32,386,816 (divisible by 4)
constexpr unsigned NVEC  = TOTAL / 4;          // 8,096,704 float4 stores
constexpr unsigned BLOCK = 256;
constexpr unsigned GRID  = (NVEC + BLOCK - 1) / BLOCK;   // 31,628

__global__ __launch_bounds__(BLOCK) void unfold_kernel(const float* __restrict__ x,
                                                       float* __restrict__ out) {
    unsigned t = blockIdx.x * BLOCK + threadIdx.x;   // float4 index
    if (t >= NVEC) return;
    unsigned o = t * 4u;                             // flat output element index

    unsigned b = o / PERB;            // unsigned magic-mul
    unsigned q = o - b * PERB;
    unsigned i = q / W_;              // unsigned magic-mul
    unsigned j = q - i * W_;
    unsigned src0 = b * L_ + i + j;

    // window-wrap: j+k >= 31 -> i+1, j-31+k  => src0 + k - 30
    unsigned s1 = src0 + 1u - ((j + 1u >= W_) ? 30u : 0u);
    unsigned s2 = src0 + 2u - ((j + 2u >= W_) ? 30u : 0u);
    unsigned s3 = src0 + 3u - ((j + 3u >= W_) ? 30u : 0u);

    if (q + 3u >= PERB) {             // rare: crosses into next batch row
        unsigned nb = (b + 1u) * L_;
        if (q + 1u >= PERB) s1 = nb + (q + 1u - PERB);
        if (q + 2u >= PERB) s2 = nb + (q + 2u - PERB);
        if (q + 3u >= PERB) s3 = nb + (q + 3u - PERB);
    }

    vfloat4 f4;
    f4.x = x[src0];
    f4.y = x[s1];
    f4.z = x[s2];
    f4.w = x[s3];
    __builtin_nontemporal_store(f4, reinterpret_cast<vfloat4*>(out) + t);
}

extern "C" void kernel_launch(void* const* d_in, const int* in_sizes, int n_in,
                              void* d_out, int out_size, void* d_ws, size_t ws_size,
                              hipStream_t stream) {
    const float* x = (const float*)d_in[0];
    float* out = (float*)d_out;
    unfold_kernel<<<GRID, BLOCK, 0, stream>>>(x, out);
}